// Round 1
// baseline (418.112 us; speedup 1.0000x reference)
//
#include <hip/hip_runtime.h>

// RoPE: x (4, 32, 8192, 64) fp32, token_positions (8192,) int32.
// Interleaved pairing: pair k = (x[2k], x[2k+1]), angle = pos * theta^(-2k/64).
// Memory-bound: 536.9 MB total HBM traffic -> ~85 us floor at 6.3 TB/s.

#define D_K 64
#define SEQ 8192
#define N_VEC4 (4u * 32u * 8192u * (D_K / 4))  // 16,777,216 float4s

// -log2(10000) / 32  (since inv_freq[k] = 10000^(-2k/64) = 2^(-log2(1e4)*k/32))
#define NEG_L2_THETA_OVER_32 (-0.41524101186092573f)

__global__ __launch_bounds__(256) void rope_kernel(
    const float4* __restrict__ x,
    const int* __restrict__ token_positions,
    float4* __restrict__ out)
{
    const unsigned i = blockIdx.x * 256u + threadIdx.x;  // float4 index

    // element offset e = i*4; within-row pair index of first pair:
    const unsigned k0  = (i * 2u) & 31u;         // ((e & 63) >> 1)
    const unsigned row = (i >> 4) & (SEQ - 1u);  // (e >> 6) % 8192

    const float p = (float)token_positions[row];

    const float inv0 = exp2f(NEG_L2_THETA_OVER_32 * (float)k0);
    const float inv1 = exp2f(NEG_L2_THETA_OVER_32 * (float)(k0 + 1u));

    float s0, c0, s1, c1;
    sincosf(p * inv0, &s0, &c0);
    sincosf(p * inv1, &s1, &c1);

    const float4 v = x[i];
    float4 r;
    r.x = c0 * v.x - s0 * v.y;
    r.y = s0 * v.x + c0 * v.y;
    r.z = c1 * v.z - s1 * v.w;
    r.w = s1 * v.z + c1 * v.w;
    out[i] = r;
}

extern "C" void kernel_launch(void* const* d_in, const int* in_sizes, int n_in,
                              void* d_out, int out_size, void* d_ws, size_t ws_size,
                              hipStream_t stream)
{
    const float4* x = (const float4*)d_in[0];
    const int* token_positions = (const int*)d_in[1];
    float4* out = (float4*)d_out;

    const unsigned nblocks = N_VEC4 / 256u;  // 65,536
    rope_kernel<<<dim3(nblocks), dim3(256), 0, stream>>>(x, token_positions, out);
}

// Round 2
// 414.779 us; speedup vs baseline: 1.0080x; 1.0080x over previous
//
#include <hip/hip_runtime.h>

// RoPE: x (4, 32, 8192, 64) fp32, token_positions (8192,) int32.
// Interleaved pairing: pair k = (x[2k], x[2k+1]), angle = pos * theta^(-2k/64).
// Memory-bound target: 536.9 MB HBM traffic -> ~90 us floor at 6.3 TB/s.
//
// R1: libm sincosf took the Payne-Hanek large-arg slow path (angles up to
// 8191 rad) -> VALU-bound at 418 us. Use HW v_sin_f32/v_cos_f32 (input in
// revolutions, v_fract reduction) instead: ~1e-3 abs error, threshold 0.114.

#define D_K 64
#define SEQ 8192
#define N_VEC4 (4u * 32u * 8192u * (D_K / 4))  // 16,777,216 float4s

// -log2(10000) / 32  (inv_freq[k] = 10000^(-2k/64) = 2^(-log2(1e4)*k/32))
#define NEG_L2_THETA_OVER_32 (-0.41524101186092573f)
#define INV_2PI 0.15915494309189535f

__device__ __forceinline__ void fast_sincos(float a, float* s, float* c) {
    // angle (radians) -> revolutions -> fract -> HW sin/cos
    float rev = a * INV_2PI;
    rev = __builtin_amdgcn_fractf(rev);
    *s = __builtin_amdgcn_sinf(rev);
    *c = __builtin_amdgcn_cosf(rev);
}

__global__ __launch_bounds__(256) void rope_kernel(
    const float4* __restrict__ x,
    const int* __restrict__ token_positions,
    float4* __restrict__ out)
{
    const unsigned i = blockIdx.x * 256u + threadIdx.x;  // float4 index

    // element offset e = i*4; within-row pair index of first pair:
    const unsigned k0  = (i * 2u) & 31u;         // ((e & 63) >> 1)
    const unsigned row = (i >> 4) & (SEQ - 1u);  // (e >> 6) % 8192

    const float p = (float)token_positions[row];

    const float inv0 = exp2f(NEG_L2_THETA_OVER_32 * (float)k0);
    const float inv1 = exp2f(NEG_L2_THETA_OVER_32 * (float)(k0 + 1u));

    float s0, c0, s1, c1;
    fast_sincos(p * inv0, &s0, &c0);
    fast_sincos(p * inv1, &s1, &c1);

    const float4 v = x[i];
    float4 r;
    r.x = c0 * v.x - s0 * v.y;
    r.y = s0 * v.x + c0 * v.y;
    r.z = c1 * v.z - s1 * v.w;
    r.w = s1 * v.z + c1 * v.w;
    out[i] = r;
}

extern "C" void kernel_launch(void* const* d_in, const int* in_sizes, int n_in,
                              void* d_out, int out_size, void* d_ws, size_t ws_size,
                              hipStream_t stream)
{
    const float4* x = (const float4*)d_in[0];
    const int* token_positions = (const int*)d_in[1];
    float4* out = (float4*)d_out;

    const unsigned nblocks = N_VEC4 / 256u;  // 65,536
    rope_kernel<<<dim3(nblocks), dim3(256), 0, stream>>>(x, token_positions, out);
}